// Round 1
// baseline (743.039 us; speedup 1.0000x reference)
//
#include <hip/hip_runtime.h>
#include <hip/hip_bf16.h>

// Problem constants (SelfAttention decode step)
#define B_    32
#define DIM_  4096
#define HQ_   32
#define HKV_  8
#define HD_   128
#define TSEQ  2048      // start_pos + 1
#define LASTT 2047
#define NCHUNK 4
#define CHUNK  512      // TSEQ / NCHUNK

__device__ __forceinline__ float dot4(float4 a, float4 b) {
    return fmaf(a.x, b.x, fmaf(a.y, b.y, fmaf(a.z, b.z, a.w * b.w)));
}

// ---------------------------------------------------------------------------
// K1: QKV projection + RoPE. One block = 8 consecutive rows of [wq;wk;wv]
// (6144 rows total) x all 32 batches. Lane l = (row i = l>>3, k-slice s = l&7).
// Each lane accumulates a 512-element partial dot; reduce-scatter over the 8
// slice-lanes leaves lane s holding batch (wave*8+s). RoPE pairs rows via
// shfl_xor(.,8). q gets 1/sqrt(128) folded in.
// ---------------------------------------------------------------------------
__global__ __launch_bounds__(256) void k1_qkv(
    const float* __restrict__ x,  const float* __restrict__ wq,
    const float* __restrict__ wk, const float* __restrict__ wv,
    const float* __restrict__ fcos, const float* __restrict__ fsin,
    float* __restrict__ q_ws, float* __restrict__ k_ws, float* __restrict__ v_ws) {
    const int tid  = threadIdx.x;
    const int wave = tid >> 6, lane = tid & 63;
    const int i = lane >> 3, s = lane & 7;
    const int rbase = blockIdx.x * 8;
    const float* W; int row0, kind;
    if (rbase < 4096)      { W = wq; row0 = rbase;        kind = 0; }
    else if (rbase < 5120) { W = wk; row0 = rbase - 4096; kind = 1; }
    else                   { W = wv; row0 = rbase - 5120; kind = 2; }
    const int row = row0 + i;
    const float4* wr = (const float4*)(W + (size_t)row * DIM_) + s * 128;
    const float4* xp = (const float4*)(x) + s * 128;
    const int bb0 = wave * 8;
    float acc[8] = {0.f,0.f,0.f,0.f,0.f,0.f,0.f,0.f};
    for (int kk = 0; kk < 128; ++kk) {
        const float4 w4 = wr[kk];
        #pragma unroll
        for (int bb = 0; bb < 8; ++bb) {
            const float4 x4 = xp[(size_t)(bb0 + bb) * 1024 + kk];
            acc[bb] = fmaf(w4.x, x4.x, acc[bb]);
            acc[bb] = fmaf(w4.y, x4.y, acc[bb]);
            acc[bb] = fmaf(w4.z, x4.z, acc[bb]);
            acc[bb] = fmaf(w4.w, x4.w, acc[bb]);
        }
    }
    // reduce-scatter across slice lanes: after 3 stages lane s holds batch bb0+s
    #pragma unroll
    for (int bb = 0; bb < 4; ++bb) {
        const float send = (s & 4) ? acc[bb] : acc[bb + 4];
        const float recv = __shfl_xor(send, 4);
        acc[bb] = ((s & 4) ? acc[bb + 4] : acc[bb]) + recv;
    }
    #pragma unroll
    for (int bb = 0; bb < 2; ++bb) {
        const float send = (s & 2) ? acc[bb] : acc[bb + 2];
        const float recv = __shfl_xor(send, 2);
        acc[bb] = ((s & 2) ? acc[bb + 2] : acc[bb]) + recv;
    }
    {
        const float send = (s & 1) ? acc[0] : acc[1];
        const float recv = __shfl_xor(send, 1);
        acc[0] = ((s & 1) ? acc[1] : acc[0]) + recv;
    }
    float val = acc[0];
    const int b = bb0 + s;
    if (kind <= 1) {  // RoPE on q and k
        const int d = row & 127;
        const float cj = fcos[d >> 1], sj = fsin[d >> 1];
        const float partner = __shfl_xor(val, 8);   // row ^ 1, same batch
        val = ((row & 1) == 0) ? (val * cj - partner * sj)
                               : (partner * sj + val * cj);
        if (kind == 0) val *= 0.08838834764831845f; // fold 1/sqrt(128) into q
    }
    if (kind == 0)      q_ws[(size_t)b * 4096 + row] = val;
    else if (kind == 1) k_ws[(size_t)b * 1024 + row] = val;
    else                v_ws[(size_t)b * 1024 + row] = val;
}

// ---------------------------------------------------------------------------
// K2: flash-style attention partials. Block = (b, kv-head g, chunk c of 512
// positions). 4 waves x 128 positions each. Scores: lane owns a position,
// scattered float4 K loads, 4 GQA heads fused per load. Position 2047 is
// sourced from k_ws/v_ws (inputs are never mutated). PV: lane = (half, col),
// coalesced V loads. Emits per-chunk (out[4][128], m[4], s[4]).
// ---------------------------------------------------------------------------
__global__ __launch_bounds__(256) void k2_attn(
    const float* __restrict__ q_ws, const float* __restrict__ k_ws,
    const float* __restrict__ v_ws, const float* __restrict__ cK,
    const float* __restrict__ cV,   float* __restrict__ cws) {
    __shared__ float p_lds[4][520];
    __shared__ float pacc[4][4][128];
    __shared__ float wred[4][4];
    __shared__ float wsum[4][4];
    const int blk = blockIdx.x;
    const int b = blk >> 5, g = (blk >> 2) & 7, c = blk & 3;
    const int tid = threadIdx.x, wave = tid >> 6, lane = tid & 63;
    const float* qb = q_ws + ((size_t)b * 32 + g * 4) * 128;
    const int tbase = c * CHUNK + wave * 128;

    float sc[2][4];
    #pragma unroll
    for (int pass = 0; pass < 2; ++pass) {
        const int t = tbase + pass * 64 + lane;
        const float4* kp = (t == LASTT)
            ? (const float4*)(k_ws + ((size_t)b * 8 + g) * 128)
            : (const float4*)(cK + (((size_t)b * TSEQ + t) * 8 + g) * 128);
        float s0 = 0.f, s1 = 0.f, s2 = 0.f, s3 = 0.f;
        for (int d4 = 0; d4 < 32; ++d4) {
            const float4 kv = kp[d4];
            const float4 q0 = ((const float4*)(qb      ))[d4];
            const float4 q1 = ((const float4*)(qb + 128))[d4];
            const float4 q2 = ((const float4*)(qb + 256))[d4];
            const float4 q3 = ((const float4*)(qb + 384))[d4];
            s0 += dot4(q0, kv); s1 += dot4(q1, kv);
            s2 += dot4(q2, kv); s3 += dot4(q3, kv);
        }
        sc[pass][0] = s0; sc[pass][1] = s1; sc[pass][2] = s2; sc[pass][3] = s3;
    }
    // block max per head
    #pragma unroll
    for (int r = 0; r < 4; ++r) {
        float m = fmaxf(sc[0][r], sc[1][r]);
        #pragma unroll
        for (int msk = 32; msk >= 1; msk >>= 1) m = fmaxf(m, __shfl_xor(m, msk));
        if (lane == 0) wred[wave][r] = m;
    }
    __syncthreads();
    float M[4], S[4];
    #pragma unroll
    for (int r = 0; r < 4; ++r)
        M[r] = fmaxf(fmaxf(wred[0][r], wred[1][r]), fmaxf(wred[2][r], wred[3][r]));
    // exp, stash p, block sum per head
    #pragma unroll
    for (int r = 0; r < 4; ++r) {
        const float p0 = __expf(sc[0][r] - M[r]);
        const float p1 = __expf(sc[1][r] - M[r]);
        p_lds[r][wave * 128 + lane]      = p0;
        p_lds[r][wave * 128 + 64 + lane] = p1;
        float su = p0 + p1;
        #pragma unroll
        for (int msk = 32; msk >= 1; msk >>= 1) su += __shfl_xor(su, msk);
        if (lane == 0) wsum[wave][r] = su;
    }
    __syncthreads();
    #pragma unroll
    for (int r = 0; r < 4; ++r)
        S[r] = wsum[0][r] + wsum[1][r] + wsum[2][r] + wsum[3][r];

    // PV: lane = (h = t parity, col = d/4). Coalesced V loads (2x512B / instr).
    const int h = lane >> 5, col = lane & 31;
    float a[4][4];
    #pragma unroll
    for (int r = 0; r < 4; ++r) {
        #pragma unroll
        for (int j = 0; j < 4; ++j) a[r][j] = 0.f;
    }
    for (int tt = 0; tt < 64; ++tt) {
        const int t = tbase + tt * 2 + h;
        const float4* vp = (t == LASTT)
            ? (const float4*)(v_ws + ((size_t)b * 8 + g) * 128)
            : (const float4*)(cV + (((size_t)b * TSEQ + t) * 8 + g) * 128);
        const float4 vv = vp[col];
        #pragma unroll
        for (int r = 0; r < 4; ++r) {
            const float pr = p_lds[r][wave * 128 + tt * 2 + h];
            a[r][0] = fmaf(pr, vv.x, a[r][0]);
            a[r][1] = fmaf(pr, vv.y, a[r][1]);
            a[r][2] = fmaf(pr, vv.z, a[r][2]);
            a[r][3] = fmaf(pr, vv.w, a[r][3]);
        }
    }
    #pragma unroll
    for (int r = 0; r < 4; ++r) {
        #pragma unroll
        for (int j = 0; j < 4; ++j) a[r][j] += __shfl_xor(a[r][j], 32);
    }
    if (lane < 32) {
        #pragma unroll
        for (int r = 0; r < 4; ++r) {
            float4* dst = (float4*)&pacc[wave][r][col * 4];
            *dst = make_float4(a[r][0], a[r][1], a[r][2], a[r][3]);
        }
    }
    __syncthreads();
    const size_t base = ((((size_t)b * 8 + g) * 4 + c) * 4) * 130;
    for (int o = tid; o < 512; o += 256) {
        const int r = o >> 7, d = o & 127;
        cws[base + r * 130 + d] =
            pacc[0][r][d] + pacc[1][r][d] + pacc[2][r][d] + pacc[3][r][d];
    }
    if (tid == 0) {
        cws[base + 0 * 130 + 128] = M[0]; cws[base + 0 * 130 + 129] = S[0];
        cws[base + 1 * 130 + 128] = M[1]; cws[base + 1 * 130 + 129] = S[1];
        cws[base + 2 * 130 + 128] = M[2]; cws[base + 2 * 130 + 129] = S[2];
        cws[base + 3 * 130 + 128] = M[3]; cws[base + 3 * 130 + 129] = S[3];
    }
}

// ---------------------------------------------------------------------------
// K3: flash combine over the 4 chunks. Block = (b, g); wave r = GQA head.
// ---------------------------------------------------------------------------
__global__ __launch_bounds__(256) void k3_comb(const float* __restrict__ cws,
                                               float* __restrict__ attn) {
    const int blk = blockIdx.x;       // b*8 + g
    const int b = blk >> 3, g = blk & 7;
    const int tid = threadIdx.x, r = tid >> 6, lane = tid & 63;
    const size_t base0 = (((size_t)b * 8 + g) * 16 + r) * 130;  // chunk stride 520
    float mi[4], si[4];
    float Mg = -3.4e38f;
    #pragma unroll
    for (int ci = 0; ci < 4; ++ci) {
        mi[ci] = cws[base0 + (size_t)ci * 520 + 128];
        si[ci] = cws[base0 + (size_t)ci * 520 + 129];
        Mg = fmaxf(Mg, mi[ci]);
    }
    float w[4], Sg = 0.f;
    #pragma unroll
    for (int ci = 0; ci < 4; ++ci) {
        w[ci] = __expf(mi[ci] - Mg);
        Sg = fmaf(si[ci], w[ci], Sg);
    }
    const float inv = 1.f / Sg;
    #pragma unroll
    for (int dd = 0; dd < 2; ++dd) {
        const int d = lane + dd * 64;
        float o = 0.f;
        #pragma unroll
        for (int ci = 0; ci < 4; ++ci)
            o = fmaf(cws[base0 + (size_t)ci * 520 + d], w[ci], o);
        attn[((size_t)b * 32 + g * 4 + r) * 128 + d] = o * inv;
    }
}

// ---------------------------------------------------------------------------
// K4: output projection out[b][d] = sum_j attn[b][j] * wo[d][j]. Same
// structure as K1 (8 rows x 32 batches per block), no RoPE.
// ---------------------------------------------------------------------------
__global__ __launch_bounds__(256) void k4_out(
    const float* __restrict__ attn, const float* __restrict__ wo,
    float* __restrict__ out) {
    const int tid  = threadIdx.x;
    const int wave = tid >> 6, lane = tid & 63;
    const int i = lane >> 3, s = lane & 7;
    const int row = blockIdx.x * 8 + i;
    const float4* wr = (const float4*)(wo + (size_t)row * 4096) + s * 128;
    const float4* ap = (const float4*)(attn) + s * 128;
    const int bb0 = wave * 8;
    float acc[8] = {0.f,0.f,0.f,0.f,0.f,0.f,0.f,0.f};
    for (int kk = 0; kk < 128; ++kk) {
        const float4 w4 = wr[kk];
        #pragma unroll
        for (int bb = 0; bb < 8; ++bb) {
            const float4 x4 = ap[(size_t)(bb0 + bb) * 1024 + kk];
            acc[bb] = fmaf(w4.x, x4.x, acc[bb]);
            acc[bb] = fmaf(w4.y, x4.y, acc[bb]);
            acc[bb] = fmaf(w4.z, x4.z, acc[bb]);
            acc[bb] = fmaf(w4.w, x4.w, acc[bb]);
        }
    }
    #pragma unroll
    for (int bb = 0; bb < 4; ++bb) {
        const float send = (s & 4) ? acc[bb] : acc[bb + 4];
        const float recv = __shfl_xor(send, 4);
        acc[bb] = ((s & 4) ? acc[bb + 4] : acc[bb]) + recv;
    }
    #pragma unroll
    for (int bb = 0; bb < 2; ++bb) {
        const float send = (s & 2) ? acc[bb] : acc[bb + 2];
        const float recv = __shfl_xor(send, 2);
        acc[bb] = ((s & 2) ? acc[bb + 2] : acc[bb]) + recv;
    }
    {
        const float send = (s & 1) ? acc[0] : acc[1];
        const float recv = __shfl_xor(send, 1);
        acc[0] = ((s & 1) ? acc[1] : acc[0]) + recv;
    }
    out[(size_t)(bb0 + s) * 4096 + row] = acc[0];
}

// ---------------------------------------------------------------------------
// Workspace layout (floats): q_ws 131072 | k_ws 32768 | v_ws 32768 |
// cws 32*8*4*4*130 = 532480 | attn 131072  => ~3.44 MB total.
// ---------------------------------------------------------------------------
extern "C" void kernel_launch(void* const* d_in, const int* in_sizes, int n_in,
                              void* d_out, int out_size, void* d_ws, size_t ws_size,
                              hipStream_t stream) {
    const float* x    = (const float*)d_in[0];
    const float* wq   = (const float*)d_in[1];
    const float* wk   = (const float*)d_in[2];
    const float* wv   = (const float*)d_in[3];
    const float* wo   = (const float*)d_in[4];
    const float* cK   = (const float*)d_in[5];
    const float* cV   = (const float*)d_in[6];
    const float* fcos = (const float*)d_in[7];
    const float* fsin = (const float*)d_in[8];
    float* ws   = (float*)d_ws;
    float* q_ws = ws;
    float* k_ws = ws + 131072;
    float* v_ws = ws + 163840;
    float* cws  = ws + 196608;
    float* attn = ws + 729088;
    float* out  = (float*)d_out;

    hipLaunchKernelGGL(k1_qkv, dim3(768), dim3(256), 0, stream,
                       x, wq, wk, wv, fcos, fsin, q_ws, k_ws, v_ws);
    hipLaunchKernelGGL(k2_attn, dim3(1024), dim3(256), 0, stream,
                       q_ws, k_ws, v_ws, cK, cV, cws);
    hipLaunchKernelGGL(k3_comb, dim3(256), dim3(256), 0, stream, cws, attn);
    hipLaunchKernelGGL(k4_out, dim3(512), dim3(256), 0, stream, attn, wo, out);
}

// Round 2
// 313.800 us; speedup vs baseline: 2.3679x; 2.3679x over previous
//
#include <hip/hip_runtime.h>
#include <hip/hip_bf16.h>

// Problem constants (SelfAttention decode step)
#define B_    32
#define DIM_  4096
#define HQ_   32
#define HKV_  8
#define HD_   128
#define TSEQ  2048      // start_pos + 1
#define LASTT 2047
#define CHUNK 512       // TSEQ / 4
#define SCL   0.08838834764831845f   // 1/sqrt(128)

__device__ __forceinline__ float dot4(float4 a, float4 b) {
    return fmaf(a.x, b.x, fmaf(a.y, b.y, fmaf(a.z, b.z, a.w * b.w)));
}

// ---------------------------------------------------------------------------
// K1: QKV projection + RoPE as an LDS-tiled SGEMM.
// Block = 32 consecutive rows of [wq;wk;wv] x 32 batches, K=4096, BK=64.
// Tiles stored K-major (wT[k][row], xT[k][b], pad to 34 for bank spread +
// 8B alignment). Thread (tr,tc) owns rows {2tr,2tr+1} x batches {2tc,2tc+1}
// -> the RoPE (even,odd) row pair lives inside one thread.
// Grid: 192 blocks (128 q, 32 k, 32 v) -- each tile entirely in one matrix.
// ---------------------------------------------------------------------------
__global__ __launch_bounds__(256) void k1_qkv(
    const float* __restrict__ x,  const float* __restrict__ wq,
    const float* __restrict__ wk, const float* __restrict__ wv,
    const float* __restrict__ fcos, const float* __restrict__ fsin,
    float* __restrict__ q_ws, float* __restrict__ k_ws, float* __restrict__ v_ws) {
    __shared__ float wT[64][34];
    __shared__ float xT[64][34];
    const int tid = threadIdx.x;
    const int rbase = blockIdx.x * 32;
    const float* W; int rloc, kind;
    if (rbase < 4096)      { W = wq; rloc = rbase;        kind = 0; }
    else if (rbase < 5120) { W = wk; rloc = rbase - 4096; kind = 1; }
    else                   { W = wv; rloc = rbase - 5120; kind = 2; }
    const int lrow = tid >> 3;        // 0..31 staging row / batch
    const int lf4  = tid & 7;         // 0..7  staging float4 lane
    const int tr2 = (tid >> 4) * 2;   // compute rows
    const int tc2 = (tid & 15) * 2;   // compute batches
    const float4* Wrow = (const float4*)(W + (size_t)(rloc + lrow) * DIM_);
    const float4* Xrow = (const float4*)(x + (size_t)lrow * DIM_);
    float c00 = 0.f, c01 = 0.f, c10 = 0.f, c11 = 0.f;

    for (int k0 = 0; k0 < 1024; k0 += 16) {      // k0 in float4 units, 64 floats/step
        #pragma unroll
        for (int j = 0; j < 2; ++j) {
            const int f = lf4 + 8 * j;           // 0..15
            const float4 w4 = Wrow[k0 + f];
            const float4 x4 = Xrow[k0 + f];
            wT[f*4+0][lrow] = w4.x; wT[f*4+1][lrow] = w4.y;
            wT[f*4+2][lrow] = w4.z; wT[f*4+3][lrow] = w4.w;
            xT[f*4+0][lrow] = x4.x; xT[f*4+1][lrow] = x4.y;
            xT[f*4+2][lrow] = x4.z; xT[f*4+3][lrow] = x4.w;
        }
        __syncthreads();
        #pragma unroll 8
        for (int k = 0; k < 64; ++k) {
            const float2 wv2 = *(const float2*)&wT[k][tr2];
            const float2 xv2 = *(const float2*)&xT[k][tc2];
            c00 = fmaf(wv2.x, xv2.x, c00);
            c01 = fmaf(wv2.x, xv2.y, c01);
            c10 = fmaf(wv2.y, xv2.x, c10);
            c11 = fmaf(wv2.y, xv2.y, c11);
        }
        __syncthreads();
    }

    // epilogue: RoPE on q/k (rows 2tr2 even/odd pair within this thread)
    const int grow = rbase + tr2;                 // global row (even)
    if (kind <= 1) {
        const int d = grow & 127;
        const float cj = fcos[d >> 1], sj = fsin[d >> 1];
        float e0 = c00 * cj - c10 * sj, o0 = c00 * sj + c10 * cj;
        float e1 = c01 * cj - c11 * sj, o1 = c01 * sj + c11 * cj;
        if (kind == 0) { e0 *= SCL; o0 *= SCL; e1 *= SCL; o1 *= SCL; }
        c00 = e0; c10 = o0; c01 = e1; c11 = o1;
    }
    float* dst = (kind == 0) ? q_ws : (kind == 1 ? k_ws : v_ws);
    const int stride = (kind == 0) ? 4096 : 1024;
    const int row0 = rloc + tr2;
    dst[(size_t)tc2 * stride + row0]         = c00;
    dst[(size_t)tc2 * stride + row0 + 1]     = c10;
    dst[(size_t)(tc2+1) * stride + row0]     = c01;
    dst[(size_t)(tc2+1) * stride + row0 + 1] = c11;
}

// ---------------------------------------------------------------------------
// K2: flash-style attention partials. Block = (b, kv-head g, chunk c of 512).
// 4 waves x 128 positions. Score phase: 8 lanes per position (s = lane&7 owns
// a d-slice), coalesced K reads (8 positions x 128B contiguous per instr),
// q fragments preloaded in registers, 3-stage shfl_xor dot reduce. Raw scores
// parked in p_lds (wave-local region, in-wave DS ordering). Softmax across
// block via wred/wsum. PV phase: lane = (t-parity, d-column), coalesced V.
// Position 2047 sourced from k_ws/v_ws (inputs never mutated).
// ---------------------------------------------------------------------------
__global__ __launch_bounds__(256) void k2_attn(
    const float* __restrict__ q_ws, const float* __restrict__ k_ws,
    const float* __restrict__ v_ws, const float* __restrict__ cK,
    const float* __restrict__ cV,   float* __restrict__ cws) {
    __shared__ float p_lds[4][520];
    __shared__ float pacc[4][4][128];
    __shared__ float wred[4][4];
    __shared__ float wsum[4][4];
    const int blk = blockIdx.x;
    const int b = blk >> 5, g = (blk >> 2) & 7, c = blk & 3;
    const int tid = threadIdx.x, wave = tid >> 6, lane = tid & 63;
    const int tbase = c * CHUNK + wave * 128;
    const int s = lane & 7, pown = lane >> 3;     // d-slice lane, position owner

    // preload q fragments: q4[r][j] covers d = (j*8+s)*4 .. +3 of head g*4+r
    const float4* qb4 = (const float4*)(q_ws + ((size_t)b * 32 + g * 4) * 128);
    float4 q4[4][4];
    #pragma unroll
    for (int r = 0; r < 4; ++r)
        #pragma unroll
        for (int j = 0; j < 4; ++j)
            q4[r][j] = qb4[r * 32 + j * 8 + s];

    // ---- score phase ----
    for (int pg = 0; pg < 16; ++pg) {
        const int t = tbase + pg * 8 + pown;
        const float4* kr = (t == LASTT)
            ? (const float4*)(k_ws + ((size_t)b * 8 + g) * 128)
            : (const float4*)(cK + (((size_t)b * TSEQ + t) * 8 + g) * 128);
        float a0 = 0.f, a1 = 0.f, a2 = 0.f, a3 = 0.f;
        #pragma unroll
        for (int j = 0; j < 4; ++j) {
            const float4 k4 = kr[j * 8 + s];
            a0 += dot4(q4[0][j], k4);
            a1 += dot4(q4[1][j], k4);
            a2 += dot4(q4[2][j], k4);
            a3 += dot4(q4[3][j], k4);
        }
        #pragma unroll
        for (int m = 4; m >= 1; m >>= 1) {
            a0 += __shfl_xor(a0, m); a1 += __shfl_xor(a1, m);
            a2 += __shfl_xor(a2, m); a3 += __shfl_xor(a3, m);
        }
        const int idx = wave * 128 + pg * 8 + pown;
        if (s == 0) p_lds[0][idx] = a0;
        if (s == 1) p_lds[1][idx] = a1;
        if (s == 2) p_lds[2][idx] = a2;
        if (s == 3) p_lds[3][idx] = a3;
    }

    // ---- softmax ----
    float sc0[4], sc1[4];
    #pragma unroll
    for (int r = 0; r < 4; ++r) {              // wave-local reads of own region
        sc0[r] = p_lds[r][wave * 128 + lane];
        sc1[r] = p_lds[r][wave * 128 + 64 + lane];
    }
    #pragma unroll
    for (int r = 0; r < 4; ++r) {
        float m = fmaxf(sc0[r], sc1[r]);
        #pragma unroll
        for (int msk = 32; msk >= 1; msk >>= 1) m = fmaxf(m, __shfl_xor(m, msk));
        if (lane == 0) wred[wave][r] = m;
    }
    __syncthreads();
    float M[4], S[4];
    #pragma unroll
    for (int r = 0; r < 4; ++r)
        M[r] = fmaxf(fmaxf(wred[0][r], wred[1][r]), fmaxf(wred[2][r], wred[3][r]));
    #pragma unroll
    for (int r = 0; r < 4; ++r) {
        const float p0 = __expf(sc0[r] - M[r]);
        const float p1 = __expf(sc1[r] - M[r]);
        p_lds[r][wave * 128 + lane]      = p0;
        p_lds[r][wave * 128 + 64 + lane] = p1;
        float su = p0 + p1;
        #pragma unroll
        for (int msk = 32; msk >= 1; msk >>= 1) su += __shfl_xor(su, msk);
        if (lane == 0) wsum[wave][r] = su;
    }
    __syncthreads();
    #pragma unroll
    for (int r = 0; r < 4; ++r)
        S[r] = wsum[0][r] + wsum[1][r] + wsum[2][r] + wsum[3][r];

    // ---- PV phase ----
    const int h = lane >> 5, col = lane & 31;
    float a[4][4];
    #pragma unroll
    for (int r = 0; r < 4; ++r) {
        #pragma unroll
        for (int j = 0; j < 4; ++j) a[r][j] = 0.f;
    }
    for (int tt = 0; tt < 64; ++tt) {
        const int t = tbase + tt * 2 + h;
        const float4* vp = (t == LASTT)
            ? (const float4*)(v_ws + ((size_t)b * 8 + g) * 128)
            : (const float4*)(cV + (((size_t)b * TSEQ + t) * 8 + g) * 128);
        const float4 vv = vp[col];
        #pragma unroll
        for (int r = 0; r < 4; ++r) {
            const float pr = p_lds[r][wave * 128 + tt * 2 + h];
            a[r][0] = fmaf(pr, vv.x, a[r][0]);
            a[r][1] = fmaf(pr, vv.y, a[r][1]);
            a[r][2] = fmaf(pr, vv.z, a[r][2]);
            a[r][3] = fmaf(pr, vv.w, a[r][3]);
        }
    }
    #pragma unroll
    for (int r = 0; r < 4; ++r) {
        #pragma unroll
        for (int j = 0; j < 4; ++j) a[r][j] += __shfl_xor(a[r][j], 32);
    }
    if (lane < 32) {
        #pragma unroll
        for (int r = 0; r < 4; ++r) {
            float4* dstp = (float4*)&pacc[wave][r][col * 4];
            *dstp = make_float4(a[r][0], a[r][1], a[r][2], a[r][3]);
        }
    }
    __syncthreads();
    const size_t base = ((((size_t)b * 8 + g) * 4 + c) * 4) * 130;
    for (int o = tid; o < 512; o += 256) {
        const int r = o >> 7, d = o & 127;
        cws[base + r * 130 + d] =
            pacc[0][r][d] + pacc[1][r][d] + pacc[2][r][d] + pacc[3][r][d];
    }
    if (tid == 0) {
        cws[base + 0 * 130 + 128] = M[0]; cws[base + 0 * 130 + 129] = S[0];
        cws[base + 1 * 130 + 128] = M[1]; cws[base + 1 * 130 + 129] = S[1];
        cws[base + 2 * 130 + 128] = M[2]; cws[base + 2 * 130 + 129] = S[2];
        cws[base + 3 * 130 + 128] = M[3]; cws[base + 3 * 130 + 129] = S[3];
    }
}

// ---------------------------------------------------------------------------
// K3: flash combine over the 4 chunks. Block = (b, g); wave r = GQA head.
// ---------------------------------------------------------------------------
__global__ __launch_bounds__(256) void k3_comb(const float* __restrict__ cws,
                                               float* __restrict__ attn) {
    const int blk = blockIdx.x;       // b*8 + g
    const int b = blk >> 3, g = blk & 7;
    const int tid = threadIdx.x, r = tid >> 6, lane = tid & 63;
    const size_t base0 = (((size_t)b * 8 + g) * 16 + r) * 130;  // chunk stride 520
    float mi[4], si[4];
    float Mg = -3.4e38f;
    #pragma unroll
    for (int ci = 0; ci < 4; ++ci) {
        mi[ci] = cws[base0 + (size_t)ci * 520 + 128];
        si[ci] = cws[base0 + (size_t)ci * 520 + 129];
        Mg = fmaxf(Mg, mi[ci]);
    }
    float w[4], Sg = 0.f;
    #pragma unroll
    for (int ci = 0; ci < 4; ++ci) {
        w[ci] = __expf(mi[ci] - Mg);
        Sg = fmaf(si[ci], w[ci], Sg);
    }
    const float inv = 1.f / Sg;
    #pragma unroll
    for (int dd = 0; dd < 2; ++dd) {
        const int d = lane + dd * 64;
        float o = 0.f;
        #pragma unroll
        for (int ci = 0; ci < 4; ++ci)
            o = fmaf(cws[base0 + (size_t)ci * 520 + d], w[ci], o);
        attn[((size_t)b * 32 + g * 4 + r) * 128 + d] = o * inv;
    }
}

// ---------------------------------------------------------------------------
// K4: output projection out[b][row] = sum_j attn[b][j] * wo[row][j].
// Same tiled-SGEMM structure as K1 (32 rows x 32 batches, BK=64), no RoPE.
// Grid: 128 blocks.
// ---------------------------------------------------------------------------
__global__ __launch_bounds__(256) void k4_out(
    const float* __restrict__ attn, const float* __restrict__ wo,
    float* __restrict__ out) {
    __shared__ float wT[64][34];
    __shared__ float xT[64][34];
    const int tid = threadIdx.x;
    const int rbase = blockIdx.x * 32;
    const int lrow = tid >> 3;
    const int lf4  = tid & 7;
    const int tr2 = (tid >> 4) * 2;
    const int tc2 = (tid & 15) * 2;
    const float4* Wrow = (const float4*)(wo + (size_t)(rbase + lrow) * DIM_);
    const float4* Xrow = (const float4*)(attn + (size_t)lrow * DIM_);
    float c00 = 0.f, c01 = 0.f, c10 = 0.f, c11 = 0.f;

    for (int k0 = 0; k0 < 1024; k0 += 16) {
        #pragma unroll
        for (int j = 0; j < 2; ++j) {
            const int f = lf4 + 8 * j;
            const float4 w4 = Wrow[k0 + f];
            const float4 x4 = Xrow[k0 + f];
            wT[f*4+0][lrow] = w4.x; wT[f*4+1][lrow] = w4.y;
            wT[f*4+2][lrow] = w4.z; wT[f*4+3][lrow] = w4.w;
            xT[f*4+0][lrow] = x4.x; xT[f*4+1][lrow] = x4.y;
            xT[f*4+2][lrow] = x4.z; xT[f*4+3][lrow] = x4.w;
        }
        __syncthreads();
        #pragma unroll 8
        for (int k = 0; k < 64; ++k) {
            const float2 wv2 = *(const float2*)&wT[k][tr2];
            const float2 xv2 = *(const float2*)&xT[k][tc2];
            c00 = fmaf(wv2.x, xv2.x, c00);
            c01 = fmaf(wv2.x, xv2.y, c01);
            c10 = fmaf(wv2.y, xv2.x, c10);
            c11 = fmaf(wv2.y, xv2.y, c11);
        }
        __syncthreads();
    }
    const int row0 = rbase + tr2;
    out[(size_t)tc2 * 4096 + row0]         = c00;
    out[(size_t)tc2 * 4096 + row0 + 1]     = c10;
    out[(size_t)(tc2+1) * 4096 + row0]     = c01;
    out[(size_t)(tc2+1) * 4096 + row0 + 1] = c11;
}

// ---------------------------------------------------------------------------
// Workspace layout (floats): q_ws 131072 | k_ws 32768 | v_ws 32768 |
// cws 32*8*4*4*130 = 532480 | attn 131072  => ~3.44 MB total.
// ---------------------------------------------------------------------------
extern "C" void kernel_launch(void* const* d_in, const int* in_sizes, int n_in,
                              void* d_out, int out_size, void* d_ws, size_t ws_size,
                              hipStream_t stream) {
    const float* x    = (const float*)d_in[0];
    const float* wq   = (const float*)d_in[1];
    const float* wk   = (const float*)d_in[2];
    const float* wv   = (const float*)d_in[3];
    const float* wo   = (const float*)d_in[4];
    const float* cK   = (const float*)d_in[5];
    const float* cV   = (const float*)d_in[6];
    const float* fcos = (const float*)d_in[7];
    const float* fsin = (const float*)d_in[8];
    float* ws   = (float*)d_ws;
    float* q_ws = ws;
    float* k_ws = ws + 131072;
    float* v_ws = ws + 163840;
    float* cws  = ws + 196608;
    float* attn = ws + 729088;
    float* out  = (float*)d_out;

    hipLaunchKernelGGL(k1_qkv, dim3(192), dim3(256), 0, stream,
                       x, wq, wk, wv, fcos, fsin, q_ws, k_ws, v_ws);
    hipLaunchKernelGGL(k2_attn, dim3(1024), dim3(256), 0, stream,
                       q_ws, k_ws, v_ws, cK, cV, cws);
    hipLaunchKernelGGL(k3_comb, dim3(256), dim3(256), 0, stream, cws, attn);
    hipLaunchKernelGGL(k4_out, dim3(128), dim3(256), 0, stream, attn, wo, out);
}

// Round 3
// 160.112 us; speedup vs baseline: 4.6407x; 1.9599x over previous
//
#include <hip/hip_runtime.h>
#include <hip/hip_bf16.h>

typedef float vf4 __attribute__((ext_vector_type(4)));

// Problem constants (SelfAttention decode step)
#define B_    32
#define DIM_  4096
#define TSEQ  2048
#define LASTT 2047
#define NCH   8
#define CHUNK 256            // TSEQ / NCH
#define SCL   0.08838834764831845f   // 1/sqrt(128)
#define KS    16             // K-split for projection GEMMs
#define KCH   256            // 4096 / KS
#define ROWS1 6144
#define ROWS4 4096

__device__ __forceinline__ float dotv(vf4 a, vf4 b) {
    return fmaf(a[0], b[0], fmaf(a[1], b[1], fmaf(a[2], b[2], a[3] * b[3])));
}

// ---------------------------------------------------------------------------
// Shared GEMM body: tile = 128 rows x 32 batches, K-chunk = 256 (4 BK=64
// tiles). Per-thread 4x4 micro-tile (rows rg+32i, batches bg+8j) => 2B of
// LDS read per FMA, all LDS reads/writes audited conflict-free (8 distinct
// bank-quads per instruction). Writes fp32 partials part[kc][grow][b].
// ---------------------------------------------------------------------------
__device__ __forceinline__ void gemm_tile_part(
    const float* __restrict__ W, const float* __restrict__ X,
    float* __restrict__ part, int rloc_base, int grow_base,
    int kb0, int kc, int rowsTot) {
    __shared__ __align__(16) vf4 wS[128][17];
    __shared__ __align__(16) vf4 xS[16][33];
    const int tid = threadIdx.x;
    const int rg = tid >> 3, bg = tid & 7;       // compute mapping
    const int sr4 = tid >> 4, swf = tid & 15;    // W staging mapping
    const int sb = tid >> 3, sxf = tid & 7;      // X staging mapping
    float c[4][4] = {};

    for (int tile = 0; tile < 4; ++tile) {
        const int kb4 = (kb0 + tile * 64) >> 2;     // float4 index base
        #pragma unroll
        for (int jj = 0; jj < 8; ++jj) {            // stage W: 128 rows x 16 f4
            const int row = sr4 + 16 * jj;
            wS[row][swf] =
                ((const vf4*)(W + (size_t)(rloc_base + row) * DIM_))[kb4 + swf];
        }
        #pragma unroll
        for (int jj = 0; jj < 2; ++jj) {            // stage X: 32 b x 16 f4
            const int f4i = sxf + 8 * jj;
            xS[f4i][sb] = ((const vf4*)(X + (size_t)sb * DIM_))[kb4 + f4i];
        }
        __syncthreads();
        #pragma unroll
        for (int k4 = 0; k4 < 16; ++k4) {
            const vf4 w0 = wS[rg      ][k4];
            const vf4 w1 = wS[rg + 32 ][k4];
            const vf4 w2 = wS[rg + 64 ][k4];
            const vf4 w3 = wS[rg + 96 ][k4];
            const vf4 x0 = xS[k4][bg     ];
            const vf4 x1 = xS[k4][bg + 8 ];
            const vf4 x2 = xS[k4][bg + 16];
            const vf4 x3 = xS[k4][bg + 24];
            #pragma unroll
            for (int cm = 0; cm < 4; ++cm) {
                c[0][0] = fmaf(w0[cm], x0[cm], c[0][0]);
                c[0][1] = fmaf(w0[cm], x1[cm], c[0][1]);
                c[0][2] = fmaf(w0[cm], x2[cm], c[0][2]);
                c[0][3] = fmaf(w0[cm], x3[cm], c[0][3]);
                c[1][0] = fmaf(w1[cm], x0[cm], c[1][0]);
                c[1][1] = fmaf(w1[cm], x1[cm], c[1][1]);
                c[1][2] = fmaf(w1[cm], x2[cm], c[1][2]);
                c[1][3] = fmaf(w1[cm], x3[cm], c[1][3]);
                c[2][0] = fmaf(w2[cm], x0[cm], c[2][0]);
                c[2][1] = fmaf(w2[cm], x1[cm], c[2][1]);
                c[2][2] = fmaf(w2[cm], x2[cm], c[2][2]);
                c[2][3] = fmaf(w2[cm], x3[cm], c[2][3]);
                c[3][0] = fmaf(w3[cm], x0[cm], c[3][0]);
                c[3][1] = fmaf(w3[cm], x1[cm], c[3][1]);
                c[3][2] = fmaf(w3[cm], x2[cm], c[3][2]);
                c[3][3] = fmaf(w3[cm], x3[cm], c[3][3]);
            }
        }
        __syncthreads();
    }
    float* pb = part + (size_t)kc * rowsTot * 32;
    #pragma unroll
    for (int i = 0; i < 4; ++i)
        #pragma unroll
        for (int j = 0; j < 4; ++j)
            pb[(size_t)(grow_base + rg + 32 * i) * 32 + bg + 8 * j] = c[i][j];
}

// K1: QKV projection partials. Grid = 48 rowblocks x 16 K-chunks = 768.
__global__ __launch_bounds__(256) void k1_qkv(
    const float* __restrict__ x,  const float* __restrict__ wq,
    const float* __restrict__ wk, const float* __restrict__ wv,
    float* __restrict__ part) {
    const int rb = blockIdx.x >> 4, kc = blockIdx.x & 15;
    const int rbase = rb * 128;
    const float* W; int rloc;
    if (rbase < 4096)      { W = wq; rloc = rbase; }
    else if (rbase < 5120) { W = wk; rloc = rbase - 4096; }
    else                   { W = wv; rloc = rbase - 5120; }
    gemm_tile_part(W, x, part, rloc, rbase, kc * KCH, kc, ROWS1);
}

// K1b: sum 16 partials + RoPE + scatter to q_ws/k_ws/v_ws. Grid = 384.
__global__ __launch_bounds__(256) void k1b_comb(
    const float* __restrict__ part, const float* __restrict__ fcos,
    const float* __restrict__ fsin, float* __restrict__ q_ws,
    float* __restrict__ k_ws, float* __restrict__ v_ws) {
    const int tid = threadIdx.x;
    const int b = tid & 31;
    const int row0 = (blockIdx.x * 8 + (tid >> 5)) * 2;
    float e = 0.f, o = 0.f;
    #pragma unroll
    for (int kc = 0; kc < 16; ++kc) {
        const float* pb = part + (size_t)kc * (ROWS1 * 32);
        e += pb[(size_t)row0 * 32 + b];
        o += pb[(size_t)(row0 + 1) * 32 + b];
    }
    if (row0 < 5120) {
        const int d = row0 & 127;
        const float cj = fcos[d >> 1], sj = fsin[d >> 1];
        const float re = e * cj - o * sj;
        const float ro = e * sj + o * cj;
        if (row0 < 4096) {
            q_ws[(size_t)b * 4096 + row0]     = re * SCL;
            q_ws[(size_t)b * 4096 + row0 + 1] = ro * SCL;
        } else {
            k_ws[(size_t)b * 1024 + row0 - 4096] = re;
            k_ws[(size_t)b * 1024 + row0 - 4095] = ro;
        }
    } else {
        v_ws[(size_t)b * 1024 + row0 - 5120] = e;
        v_ws[(size_t)b * 1024 + row0 - 5119] = o;
    }
}

// ---------------------------------------------------------------------------
// K2: flash attention partials. Block = (b, g, chunk of 256). 4 waves x 64
// positions. Scores: 8 lanes/position, 2-deep prefetch, nontemporal K loads.
// Wave-local softmax stats -> block combine. PV: unroll-4 nontemporal V.
// Position 2047 sourced from k_ws/v_ws (inputs never mutated).
// ---------------------------------------------------------------------------
__global__ __launch_bounds__(256) void k2_attn(
    const float* __restrict__ q_ws, const float* __restrict__ k_ws,
    const float* __restrict__ v_ws, const float* __restrict__ cK,
    const float* __restrict__ cV,   float* __restrict__ cws) {
    __shared__ __align__(16) float p_lds[4][260];
    __shared__ __align__(16) float pacc[4][4][128];
    __shared__ float wred[4][4];
    __shared__ float wsum[4][4];
    const int blk = blockIdx.x;
    const int b = blk >> 6, g = (blk >> 3) & 7, c = blk & 7;
    const int tid = threadIdx.x, wave = tid >> 6, lane = tid & 63;
    const int tbase = c * CHUNK + wave * 64;
    const int s = lane & 7, pown = lane >> 3;

    const vf4* qb4 = (const vf4*)(q_ws + ((size_t)b * 32 + g * 4) * 128);
    vf4 q4[4][4];
    #pragma unroll
    for (int r = 0; r < 4; ++r)
        #pragma unroll
        for (int j = 0; j < 4; ++j)
            q4[r][j] = qb4[r * 32 + j * 8 + s];

    const vf4* kwsrow = (const vf4*)(k_ws + ((size_t)b * 8 + g) * 128);
    const vf4* vwsrow = (const vf4*)(v_ws + ((size_t)b * 8 + g) * 128);

    // ---- score phase (2-deep software pipeline) ----
    vf4 kb[4];
    {
        const int t = tbase + pown;
        const vf4* kr = (t == LASTT) ? kwsrow
            : (const vf4*)(cK + (((size_t)b * TSEQ + t) * 8 + g) * 128);
        #pragma unroll
        for (int j = 0; j < 4; ++j)
            kb[j] = __builtin_nontemporal_load(&kr[j * 8 + s]);
    }
    #pragma unroll
    for (int pg = 0; pg < 8; ++pg) {
        vf4 kn[4];
        if (pg < 7) {
            const int t = tbase + (pg + 1) * 8 + pown;
            const vf4* kr = (t == LASTT) ? kwsrow
                : (const vf4*)(cK + (((size_t)b * TSEQ + t) * 8 + g) * 128);
            #pragma unroll
            for (int j = 0; j < 4; ++j)
                kn[j] = __builtin_nontemporal_load(&kr[j * 8 + s]);
        }
        float a0 = 0.f, a1 = 0.f, a2 = 0.f, a3 = 0.f;
        #pragma unroll
        for (int j = 0; j < 4; ++j) {
            a0 += dotv(q4[0][j], kb[j]);
            a1 += dotv(q4[1][j], kb[j]);
            a2 += dotv(q4[2][j], kb[j]);
            a3 += dotv(q4[3][j], kb[j]);
        }
        #pragma unroll
        for (int m = 4; m >= 1; m >>= 1) {
            a0 += __shfl_xor(a0, m); a1 += __shfl_xor(a1, m);
            a2 += __shfl_xor(a2, m); a3 += __shfl_xor(a3, m);
        }
        const int idx = wave * 64 + pg * 8 + pown;
        if (s == 0) p_lds[0][idx] = a0;
        if (s == 1) p_lds[1][idx] = a1;
        if (s == 2) p_lds[2][idx] = a2;
        if (s == 3) p_lds[3][idx] = a3;
        #pragma unroll
        for (int j = 0; j < 4; ++j) kb[j] = kn[j];
    }

    // ---- softmax (wave covers its own 64 positions) ----
    float sc[4];
    #pragma unroll
    for (int r = 0; r < 4; ++r) sc[r] = p_lds[r][wave * 64 + lane];
    #pragma unroll
    for (int r = 0; r < 4; ++r) {
        float m = sc[r];
        #pragma unroll
        for (int msk = 32; msk >= 1; msk >>= 1) m = fmaxf(m, __shfl_xor(m, msk));
        if (lane == 0) wred[wave][r] = m;
    }
    __syncthreads();
    float M[4], S[4];
    #pragma unroll
    for (int r = 0; r < 4; ++r)
        M[r] = fmaxf(fmaxf(wred[0][r], wred[1][r]), fmaxf(wred[2][r], wred[3][r]));
    #pragma unroll
    for (int r = 0; r < 4; ++r) {
        const float p = __expf(sc[r] - M[r]);
        p_lds[r][wave * 64 + lane] = p;
        float su = p;
        #pragma unroll
        for (int msk = 32; msk >= 1; msk >>= 1) su += __shfl_xor(su, msk);
        if (lane == 0) wsum[wave][r] = su;
    }
    __syncthreads();
    #pragma unroll
    for (int r = 0; r < 4; ++r)
        S[r] = wsum[0][r] + wsum[1][r] + wsum[2][r] + wsum[3][r];

    // ---- PV phase ----
    const int h = lane >> 5, col = lane & 31;
    float a[4][4] = {};
    #pragma unroll
    for (int tt = 0; tt < 8; ++tt) {
        vf4 vv[4];
        #pragma unroll
        for (int u = 0; u < 4; ++u) {
            const int t = tbase + tt * 8 + u * 2 + h;
            const vf4* vp = (t == LASTT) ? vwsrow
                : (const vf4*)(cV + (((size_t)b * TSEQ + t) * 8 + g) * 128);
            vv[u] = __builtin_nontemporal_load(&vp[col]);
        }
        #pragma unroll
        for (int u = 0; u < 4; ++u) {
            #pragma unroll
            for (int r = 0; r < 4; ++r) {
                const float pr = p_lds[r][wave * 64 + tt * 8 + u * 2 + h];
                a[r][0] = fmaf(pr, vv[u][0], a[r][0]);
                a[r][1] = fmaf(pr, vv[u][1], a[r][1]);
                a[r][2] = fmaf(pr, vv[u][2], a[r][2]);
                a[r][3] = fmaf(pr, vv[u][3], a[r][3]);
            }
        }
    }
    #pragma unroll
    for (int r = 0; r < 4; ++r)
        #pragma unroll
        for (int j = 0; j < 4; ++j) a[r][j] += __shfl_xor(a[r][j], 32);
    if (lane < 32) {
        #pragma unroll
        for (int r = 0; r < 4; ++r) {
            vf4 v; v[0] = a[r][0]; v[1] = a[r][1]; v[2] = a[r][2]; v[3] = a[r][3];
            *(vf4*)&pacc[wave][r][col * 4] = v;
        }
    }
    __syncthreads();
    const size_t base = (size_t)blk * 520;
    for (int o = tid; o < 512; o += 256) {
        const int r = o >> 7, d = o & 127;
        cws[base + r * 130 + d] =
            pacc[0][r][d] + pacc[1][r][d] + pacc[2][r][d] + pacc[3][r][d];
    }
    if (tid == 0) {
        #pragma unroll
        for (int r = 0; r < 4; ++r) {
            cws[base + r * 130 + 128] = M[r];
            cws[base + r * 130 + 129] = S[r];
        }
    }
}

// K3: flash combine over 8 chunks. Grid = 256 (b,g); wave = GQA head.
__global__ __launch_bounds__(256) void k3_comb(const float* __restrict__ cws,
                                               float* __restrict__ attn) {
    const int blk = blockIdx.x;       // b*8 + g
    const int b = blk >> 3, g = blk & 7;
    const int tid = threadIdx.x, r = tid >> 6, lane = tid & 63;
    const size_t base0 = (size_t)blk * 8 * 520 + r * 130;
    float mi[8], si[8];
    float Mg = -3.4e38f;
    #pragma unroll
    for (int ci = 0; ci < 8; ++ci) {
        mi[ci] = cws[base0 + (size_t)ci * 520 + 128];
        si[ci] = cws[base0 + (size_t)ci * 520 + 129];
        Mg = fmaxf(Mg, mi[ci]);
    }
    float w[8], Sg = 0.f;
    #pragma unroll
    for (int ci = 0; ci < 8; ++ci) {
        w[ci] = __expf(mi[ci] - Mg);
        Sg = fmaf(si[ci], w[ci], Sg);
    }
    const float inv = 1.f / Sg;
    #pragma unroll
    for (int dd = 0; dd < 2; ++dd) {
        const int d = lane + dd * 64;
        float o = 0.f;
        #pragma unroll
        for (int ci = 0; ci < 8; ++ci)
            o = fmaf(cws[base0 + (size_t)ci * 520 + d], w[ci], o);
        attn[((size_t)b * 32 + g * 4 + r) * 128 + d] = o * inv;
    }
}

// K4: output projection partials. Grid = 32 rowblocks x 16 K-chunks = 512.
__global__ __launch_bounds__(256) void k4_out(
    const float* __restrict__ attn, const float* __restrict__ wo,
    float* __restrict__ part) {
    const int rb = blockIdx.x >> 4, kc = blockIdx.x & 15;
    const int rbase = rb * 128;
    gemm_tile_part(wo, attn, part, rbase, rbase, kc * KCH, kc, ROWS4);
}

// K4b: sum 16 partials -> out. Grid = 512.
__global__ __launch_bounds__(256) void k4b_comb(const float* __restrict__ part,
                                                float* __restrict__ out) {
    const int tid = threadIdx.x;
    const int b = tid & 31;
    const int row = blockIdx.x * 8 + (tid >> 5);
    float acc = 0.f;
    #pragma unroll
    for (int kc = 0; kc < 16; ++kc)
        acc += part[(size_t)kc * (ROWS4 * 32) + (size_t)row * 32 + b];
    out[(size_t)b * 4096 + row] = acc;
}

// ---------------------------------------------------------------------------
// Workspace (floats), region A reused serially (part1 -> cws -> part4):
//   A:    offset 0,        3,145,728   (max of 16*6144*32, 2048*520, 16*4096*32)
//   q_ws: 3,145,728        131,072
//   k_ws: 3,276,800         32,768
//   v_ws: 3,309,568         32,768
//   attn: 3,342,336        131,072     => total ~13.9 MB
// ---------------------------------------------------------------------------
extern "C" void kernel_launch(void* const* d_in, const int* in_sizes, int n_in,
                              void* d_out, int out_size, void* d_ws, size_t ws_size,
                              hipStream_t stream) {
    const float* x    = (const float*)d_in[0];
    const float* wq   = (const float*)d_in[1];
    const float* wk   = (const float*)d_in[2];
    const float* wv   = (const float*)d_in[3];
    const float* wo   = (const float*)d_in[4];
    const float* cK   = (const float*)d_in[5];
    const float* cV   = (const float*)d_in[6];
    const float* fcos = (const float*)d_in[7];
    const float* fsin = (const float*)d_in[8];
    float* ws   = (float*)d_ws;
    float* A    = ws;                    // part1 / cws / part4 (serial reuse)
    float* q_ws = ws + 3145728;
    float* k_ws = ws + 3276800;
    float* v_ws = ws + 3309568;
    float* attn = ws + 3342336;
    float* out  = (float*)d_out;

    hipLaunchKernelGGL(k1_qkv,   dim3(768),  dim3(256), 0, stream,
                       x, wq, wk, wv, A);
    hipLaunchKernelGGL(k1b_comb, dim3(384),  dim3(256), 0, stream,
                       A, fcos, fsin, q_ws, k_ws, v_ws);
    hipLaunchKernelGGL(k2_attn,  dim3(2048), dim3(256), 0, stream,
                       q_ws, k_ws, v_ws, cK, cV, A);
    hipLaunchKernelGGL(k3_comb,  dim3(256),  dim3(256), 0, stream, A, attn);
    hipLaunchKernelGGL(k4_out,   dim3(512),  dim3(256), 0, stream, attn, wo, A);
    hipLaunchKernelGGL(k4b_comb, dim3(512),  dim3(256), 0, stream, A, out);
}